// Round 1
// baseline (232.041 us; speedup 1.0000x reference)
//
#include <hip/hip_runtime.h>
#include <hip/hip_bf16.h>
#include <stdint.h>

// ---------------------------------------------------------------------------
// GQA attention block, MI355X/gfx950, bf16 MFMA pipeline.
//   B=8 T=512 C=2048 H=16 KVH=4 D=128
// Stages: convert/transposes -> QKV GEMM -> RoPE -> V-transpose -> flash attn
//         -> output GEMM (fp32 out).
// ---------------------------------------------------------------------------

typedef __bf16 bf16x8 __attribute__((ext_vector_type(8)));
typedef float  f32x4  __attribute__((ext_vector_type(4)));
typedef float  f4     __attribute__((ext_vector_type(4)));
typedef unsigned short u16x8 __attribute__((ext_vector_type(8)));
typedef unsigned short u16x4 __attribute__((ext_vector_type(4)));
typedef unsigned short us;

__device__ __forceinline__ float bf2f(us u) {
  unsigned int x = ((unsigned int)u) << 16;
  return __builtin_bit_cast(float, x);
}
__device__ __forceinline__ us f2bf(float f) {   // round-to-nearest-even
  unsigned int x = __builtin_bit_cast(unsigned int, f);
  unsigned int r = x + 0x7fffu + ((x >> 16) & 1u);
  return (us)(r >> 16);
}

// async global->LDS, 16B per lane; LDS dest must be linear (uniform + lane*16)
__device__ __forceinline__ void gload16(const void* gsrc, void* ldst) {
  auto g = (const __attribute__((address_space(1))) void*)gsrc;
  auto l = (__attribute__((address_space(3))) void*)ldst;
  __builtin_amdgcn_global_load_lds(g, l, 16, 0, 0);
}

// ---------------------------------------------------------------------------
// small prep kernels
// ---------------------------------------------------------------------------

// fp32 -> bf16, 8 elems/thread, exact-size grid
__global__ void convx_kernel(const float* __restrict__ x, us* __restrict__ xb) {
  size_t idx = (size_t)blockIdx.x * 256 + threadIdx.x;
  const f4* p = (const f4*)(x + idx * 8);
  f4 a = p[0], b = p[1];
  u16x8 o;
#pragma unroll
  for (int e = 0; e < 4; ++e) { o[e] = f2bf(a[e]); o[4 + e] = f2bf(b[e]); }
  *(u16x8*)(xb + idx * 8) = o;
}

// transpose + convert: dst[(rowOff+n)*LD + k] = src[k*N + n], 64x64 LDS tiles
__global__ __launch_bounds__(256) void wtrans_kernel(const float* __restrict__ src,
    us* __restrict__ dst, int N, int rowOff, int LD) {
  __shared__ float lds[64][65];
  const int n0 = blockIdx.x * 64, k0 = blockIdx.y * 64;
  const int c = threadIdx.x & 63, rq = threadIdx.x >> 6;
#pragma unroll
  for (int i = 0; i < 16; ++i) {
    int r = i * 4 + rq;
    lds[r][c] = src[(size_t)(k0 + r) * N + n0 + c];
  }
  __syncthreads();
#pragma unroll
  for (int i = 0; i < 16; ++i) {
    int nr = i * 4 + rq;
    dst[(size_t)(rowOff + n0 + nr) * LD + k0 + c] = f2bf(lds[c][nr]);
  }
}

// RoPE cos/sin tables: [512][64] each, fp32
__global__ void tables_kernel(float* __restrict__ ct, float* __restrict__ st) {
  int idx = blockIdx.x * 256 + threadIdx.x;   // 32768
  int i = idx & 63, t = idx >> 6;
  // inv_freq = 10000^(-i/64) = exp2(-i * log2(10000)/64)
  float inv = exp2f(-(float)i * (13.287712379549449f / 64.0f));
  float ang = (float)t * inv;
  ct[idx] = cosf(ang);
  st[idx] = sinf(ang);
}

// in-place RoPE on Qh [128 slots][512][128] and Kh [32 slots][512][128];
// Q additionally scaled by 1/sqrt(128). 4 d-pairs per thread.
__global__ void rope_kernel(us* __restrict__ Qh, us* __restrict__ Kh,
                            const float* __restrict__ ct, const float* __restrict__ st) {
  int idx = blockIdx.x * 256 + threadIdx.x;   // 1,310,720 exact
  int dq = idx & 15;
  int t = (idx >> 4) & 511;
  int slot = idx >> 13;                       // 0..159
  bool isQ = slot < 128;
  us* rowp = isQ ? (Qh + ((size_t)slot * 512 + t) * 128)
                 : (Kh + ((size_t)(slot - 128) * 512 + t) * 128);
  int d0 = dq * 4;
  u16x4 x1 = *(const u16x4*)(rowp + d0);
  u16x4 x2 = *(const u16x4*)(rowp + 64 + d0);
  f4 c = *(const f4*)(ct + t * 64 + d0);
  f4 s = *(const f4*)(st + t * 64 + d0);
  float scale = isQ ? 0.08838834764831845f : 1.0f;
  u16x4 o1, o2;
#pragma unroll
  for (int e = 0; e < 4; ++e) {
    float a = bf2f(x1[e]), b = bf2f(x2[e]);
    o1[e] = f2bf((a * c[e] - b * s[e]) * scale);
    o2[e] = f2bf((b * c[e] + a * s[e]) * scale);
  }
  *(u16x4*)(rowp + d0) = o1;
  *(u16x4*)(rowp + 64 + d0) = o2;
}

// V [32 slots][512][128] -> Vt [32 slots][128][512], 64x64 LDS tiles
__global__ __launch_bounds__(256) void vtrans_kernel(const us* __restrict__ Vh,
                                                     us* __restrict__ Vt) {
  __shared__ us lds[64][66];
  const int bid = blockIdx.x;          // 512
  const int bhk = bid >> 4;
  const int rem = bid & 15;
  const int tt = rem >> 1, dt = rem & 1;
  const us* src = Vh + (size_t)bhk * 512 * 128;
  us* dst = Vt + (size_t)bhk * 128 * 512;
  const int c = threadIdx.x & 63, rq = threadIdx.x >> 6;
#pragma unroll
  for (int i = 0; i < 16; ++i) {
    int r = i * 4 + rq;
    lds[r][c] = src[(size_t)(tt * 64 + r) * 128 + dt * 64 + c];
  }
  __syncthreads();
#pragma unroll
  for (int i = 0; i < 16; ++i) {
    int dr = i * 4 + rq;
    dst[(size_t)(dt * 64 + dr) * 512 + tt * 64 + c] = lds[c][dr];
  }
}

// ---------------------------------------------------------------------------
// 128x128 tile bf16 GEMM core (m97 structure): A [M][K], Bt [N][K], BK=64,
// 256 threads = 4 waves (2x2), each wave 64x64 via 4x4 of 16x16x32 MFMA.
// ---------------------------------------------------------------------------
__device__ __forceinline__ void gemm128_core(const us* __restrict__ A,
    const us* __restrict__ Bt, const int K, const int m0, const int n0,
    us* AT, us* BT, f32x4 acc[4][4]) {
  const int tid = threadIdx.x;
  const int lane = tid & 63;
  const int wid = tid >> 6;
  const int wm = wid >> 1, wn = wid & 1;
  const int lr = lane & 15, lq = lane >> 4;
  const f32x4 zz = {0.f, 0.f, 0.f, 0.f};
#pragma unroll
  for (int i = 0; i < 4; ++i)
#pragma unroll
    for (int j = 0; j < 4; ++j) acc[i][j] = zz;

  const int KT = K >> 6;
  for (int kt = 0; kt < KT; ++kt) {
    __syncthreads();
    // stage A tile [128 rows][64 k] linear: chunk c -> row c>>3, kchunk c&7
#pragma unroll
    for (int it = 0; it < 4; ++it) {
      int c = it * 256 + tid;
      gload16(A + (size_t)(m0 + (c >> 3)) * K + (kt << 6) + ((c & 7) << 3),
              AT + (c << 3));
    }
#pragma unroll
    for (int it = 0; it < 4; ++it) {
      int c = it * 256 + tid;
      gload16(Bt + (size_t)(n0 + (c >> 3)) * K + (kt << 6) + ((c & 7) << 3),
              BT + (c << 3));
    }
    __syncthreads();
#pragma unroll
    for (int ks = 0; ks < 2; ++ks) {
      bf16x8 af[4], bfm[4];
#pragma unroll
      for (int i = 0; i < 4; ++i)
        af[i] = *(const bf16x8*)(AT + ((wm * 64 + i * 16 + lr) << 6) + ks * 32 + (lq << 3));
#pragma unroll
      for (int j = 0; j < 4; ++j)
        bfm[j] = *(const bf16x8*)(BT + ((wn * 64 + j * 16 + lr) << 6) + ks * 32 + (lq << 3));
#pragma unroll
      for (int i = 0; i < 4; ++i)
#pragma unroll
        for (int j = 0; j < 4; ++j)
          acc[i][j] = __builtin_amdgcn_mfma_f32_16x16x32_bf16(af[i], bfm[j], acc[i][j], 0, 0, 0);
    }
  }
}

// QKV GEMM: xb [4096][2048] @ wcat_t [3072][2048]^T, scatter to per-head bufs
__global__ __launch_bounds__(256) void gemm_qkv_kernel(const us* __restrict__ xb,
    const us* __restrict__ wcat, us* __restrict__ Qh, us* __restrict__ Kh,
    us* __restrict__ Vh) {
  __shared__ __align__(16) us AT[128 * 64];
  __shared__ __align__(16) us BT[128 * 64];
  f32x4 acc[4][4];
  const int m0 = blockIdx.y << 7, n0 = blockIdx.x << 7;
  gemm128_core(xb, wcat, 2048, m0, n0, AT, BT, acc);
  const int tid = threadIdx.x, lane = tid & 63, wid = tid >> 6;
  const int wm = wid >> 1, wn = wid & 1, lr = lane & 15, lq = lane >> 4;
#pragma unroll
  for (int i = 0; i < 4; ++i) {
#pragma unroll
    for (int j = 0; j < 4; ++j) {
      int col = n0 + wn * 64 + j * 16 + lr;
#pragma unroll
      for (int r = 0; r < 4; ++r) {
        int row = m0 + wm * 64 + i * 16 + lq * 4 + r;
        int bb = row >> 9, t = row & 511;
        us val = f2bf(acc[i][j][r]);
        if (col < 2048) {
          Qh[((size_t)(bb * 16 + (col >> 7)) * 512 + t) * 128 + (col & 127)] = val;
        } else if (col < 2560) {
          int cc = col - 2048;
          Kh[((size_t)(bb * 4 + (cc >> 7)) * 512 + t) * 128 + (cc & 127)] = val;
        } else {
          int cc = col - 2560;
          Vh[((size_t)(bb * 4 + (cc >> 7)) * 512 + t) * 128 + (cc & 127)] = val;
        }
      }
    }
  }
}

// output GEMM: Oh [4096][2048] @ wot [2048][2048]^T -> fp32 out
__global__ __launch_bounds__(256) void gemm_out_kernel(const us* __restrict__ Ob,
    const us* __restrict__ wot, float* __restrict__ out) {
  __shared__ __align__(16) us AT[128 * 64];
  __shared__ __align__(16) us BT[128 * 64];
  f32x4 acc[4][4];
  const int m0 = blockIdx.y << 7, n0 = blockIdx.x << 7;
  gemm128_core(Ob, wot, 2048, m0, n0, AT, BT, acc);
  const int tid = threadIdx.x, lane = tid & 63, wid = tid >> 6;
  const int wm = wid >> 1, wn = wid & 1, lr = lane & 15, lq = lane >> 4;
#pragma unroll
  for (int i = 0; i < 4; ++i)
#pragma unroll
    for (int j = 0; j < 4; ++j) {
      int col = n0 + wn * 64 + j * 16 + lr;
#pragma unroll
      for (int r = 0; r < 4; ++r) {
        int row = m0 + wm * 64 + i * 16 + lq * 4 + r;
        out[(size_t)row * 2048 + col] = acc[i][j][r];
      }
    }
}

// ---------------------------------------------------------------------------
// flash attention: grid (8 qblocks, 128 bh), 256 thr = 4 waves x 16 q-rows.
// K tile [64][128] and Vt tile [128][64] staged with chunk^=(row&7) XOR
// swizzle (pre-swizzled global source, linear LDS dest, swizzled reads).
// ---------------------------------------------------------------------------
__global__ __launch_bounds__(256) void attn_kernel(const us* __restrict__ Qh,
    const us* __restrict__ Kh, const us* __restrict__ Vt, us* __restrict__ Oh) {
  __shared__ __align__(16) us Ktile[64 * 128];
  __shared__ __align__(16) us Vtile[128 * 64];
  __shared__ __align__(16) us Plds[4 * 16 * 72];   // per-wave P, stride 72
  const int tid = threadIdx.x, lane = tid & 63, w = tid >> 6;
  const int lr = lane & 15, lq = lane >> 4;
  const int qb = blockIdx.x, bh = blockIdx.y;
  const int b = bh >> 4, h = bh & 15, kvh = h >> 2;
  const us* Kbh = Kh + (size_t)(b * 4 + kvh) * 512 * 128;
  const us* Vbh = Vt + (size_t)(b * 4 + kvh) * 128 * 512;

  // Q fragments (A operand): row = lr, k-chunks lq*8 + ks*32; pre-scaled
  const us* Qrow = Qh + ((size_t)bh * 512 + qb * 64 + w * 16 + lr) * 128;
  bf16x8 qf[4];
#pragma unroll
  for (int ks = 0; ks < 4; ++ks) qf[ks] = *(const bf16x8*)(Qrow + ks * 32 + (lq << 3));

  const f32x4 zz = {0.f, 0.f, 0.f, 0.f};
  f32x4 o[8];
#pragma unroll
  for (int i = 0; i < 8; ++i) o[i] = zz;
  float m[4], ll[4];
#pragma unroll
  for (int r = 0; r < 4; ++r) { m[r] = -1e30f; ll[r] = 0.f; }
  us* Pw = Plds + w * 16 * 72;

  for (int j = 0; j <= qb; ++j) {
    __syncthreads();
    // stage K tile: 64 rows x 16 chunks, source pre-swizzled
#pragma unroll
    for (int it = 0; it < 4; ++it) {
      int c = it * 256 + tid;
      int row = c >> 4, kc = c & 15;
      gload16(Kbh + (size_t)(j * 64 + row) * 128 + ((kc ^ (row & 7)) << 3),
              Ktile + (c << 3));
    }
    // stage V^T tile: 128 d-rows x 8 chunks
#pragma unroll
    for (int it = 0; it < 4; ++it) {
      int c = it * 256 + tid;
      int row = c >> 3, tc = c & 7;
      gload16(Vbh + (size_t)row * 512 + j * 64 + ((tc ^ (row & 7)) << 3),
              Vtile + (c << 3));
    }
    __syncthreads();

    // S = Q K^T  (16 q-rows x 64 kv)
    f32x4 s[4];
#pragma unroll
    for (int nb = 0; nb < 4; ++nb) s[nb] = zz;
#pragma unroll
    for (int ks = 0; ks < 4; ++ks) {
#pragma unroll
      for (int nb = 0; nb < 4; ++nb) {
        int row = nb * 16 + lr;
        bf16x8 kf = *(const bf16x8*)(Ktile + (row << 7) + (((ks * 4 + lq) ^ (row & 7)) << 3));
        s[nb] = __builtin_amdgcn_mfma_f32_16x16x32_bf16(qf[ks], kf, s[nb], 0, 0, 0);
      }
    }
    if (j == qb) {   // causal mask on the diagonal tile (local indices)
#pragma unroll
      for (int nb = 0; nb < 4; ++nb)
#pragma unroll
        for (int r = 0; r < 4; ++r)
          if (nb * 16 + lr > w * 16 + lq * 4 + r) s[nb][r] = -1e30f;
    }

    // online softmax; each q-row's 64 scores live on 16 lanes (same lq) x 4 regs
    float tm[4], alpha[4], rs[4];
#pragma unroll
    for (int r = 0; r < 4; ++r)
      tm[r] = fmaxf(fmaxf(s[0][r], s[1][r]), fmaxf(s[2][r], s[3][r]));
#pragma unroll
    for (int off = 1; off < 16; off <<= 1)
#pragma unroll
      for (int r = 0; r < 4; ++r)
        tm[r] = fmaxf(tm[r], __shfl_xor(tm[r], off, 64));
#pragma unroll
    for (int r = 0; r < 4; ++r) {
      float mn = fmaxf(m[r], tm[r]);
      alpha[r] = __expf(m[r] - mn);
      m[r] = mn;
    }
#pragma unroll
    for (int nb = 0; nb < 4; ++nb)
#pragma unroll
      for (int r = 0; r < 4; ++r)
        s[nb][r] = __expf(s[nb][r] - m[r]);
#pragma unroll
    for (int r = 0; r < 4; ++r)
      rs[r] = s[0][r] + s[1][r] + s[2][r] + s[3][r];
#pragma unroll
    for (int off = 1; off < 16; off <<= 1)
#pragma unroll
      for (int r = 0; r < 4; ++r)
        rs[r] += __shfl_xor(rs[r], off, 64);
#pragma unroll
    for (int r = 0; r < 4; ++r) ll[r] = ll[r] * alpha[r] + rs[r];
#pragma unroll
    for (int i = 0; i < 8; ++i)
#pragma unroll
      for (int r = 0; r < 4; ++r) o[i][r] *= alpha[r];

    // P (C layout) -> LDS so it can be re-read in A layout
#pragma unroll
    for (int nb = 0; nb < 4; ++nb)
#pragma unroll
      for (int r = 0; r < 4; ++r)
        Pw[(lq * 4 + r) * 72 + nb * 16 + lr] = f2bf(s[nb][r]);

    // O += P @ V
#pragma unroll
    for (int ks2 = 0; ks2 < 2; ++ks2) {
      bf16x8 pf = *(const bf16x8*)(Pw + lr * 72 + ks2 * 32 + (lq << 3));
#pragma unroll
      for (int nd = 0; nd < 8; ++nd) {
        int d = nd * 16 + lr;
        bf16x8 vf = *(const bf16x8*)(Vtile + (d << 6) + (((ks2 * 4 + lq) ^ (d & 7)) << 3));
        o[nd] = __builtin_amdgcn_mfma_f32_16x16x32_bf16(pf, vf, o[nd], 0, 0, 0);
      }
    }
  }

  float inv[4];
#pragma unroll
  for (int r = 0; r < 4; ++r) inv[r] = 1.0f / ll[r];
  const int rowb = b * 512 + qb * 64 + w * 16 + lq * 4;
  const int colb = h * 128 + lr;
#pragma unroll
  for (int nd = 0; nd < 8; ++nd)
#pragma unroll
    for (int r = 0; r < 4; ++r)
      Oh[(size_t)(rowb + r) * 2048 + colb + nd * 16] = f2bf(o[nd][r] * inv[r]);
}

// ---------------------------------------------------------------------------
extern "C" void kernel_launch(void* const* d_in, const int* in_sizes, int n_in,
                              void* d_out, int out_size, void* d_ws, size_t ws_size,
                              hipStream_t stream) {
  const float* x  = (const float*)d_in[0];
  const float* wq = (const float*)d_in[1];
  const float* wk = (const float*)d_in[2];
  const float* wv = (const float*)d_in[3];
  const float* wo = (const float*)d_in[4];
  float* out = (float*)d_out;
  char* ws = (char*)d_ws;

  us*    xb   = (us*)(ws);                    // [4096][2048] bf16      16 MB
  us*    wcat = (us*)(ws + 16777216);         // [3072][2048] bf16      12 MB
  us*    wot  = (us*)(ws + 29360128);         // [2048][2048] bf16       8 MB
  us*    Qh   = (us*)(ws + 37748736);         // [128][512][128] bf16   16 MB
  us*    Kh   = (us*)(ws + 54525952);         // [32][512][128] bf16     4 MB
  us*    Vh   = (us*)(ws + 58720256);         // [32][512][128] bf16     4 MB
  us*    Vt   = (us*)(ws + 62914560);         // [32][128][512] bf16     4 MB
  us*    Oh   = (us*)(ws + 67108864);         // [4096][2048] bf16      16 MB
  float* ct   = (float*)(ws + 83886080);      // [512][64] fp32
  float* st   = (float*)(ws + 84017152);      // [512][64] fp32

  convx_kernel<<<4096, 256, 0, stream>>>(x, xb);
  wtrans_kernel<<<dim3(32, 32), 256, 0, stream>>>(wq, wcat, 2048, 0, 2048);
  wtrans_kernel<<<dim3(8, 32), 256, 0, stream>>>(wk, wcat, 512, 2048, 2048);
  wtrans_kernel<<<dim3(8, 32), 256, 0, stream>>>(wv, wcat, 512, 2560, 2048);
  wtrans_kernel<<<dim3(32, 32), 256, 0, stream>>>(wo, wot, 2048, 0, 2048);
  tables_kernel<<<128, 256, 0, stream>>>(ct, st);

  gemm_qkv_kernel<<<dim3(24, 32), 256, 0, stream>>>(xb, wcat, Qh, Kh, Vh);
  rope_kernel<<<5120, 256, 0, stream>>>(Qh, Kh, ct, st);
  vtrans_kernel<<<512, 256, 0, stream>>>(Vh, Vt);
  attn_kernel<<<dim3(8, 128), 256, 0, stream>>>(Qh, Kh, Vt, Oh);
  gemm_out_kernel<<<dim3(16, 32), 256, 0, stream>>>(Oh, wot, out);
}

// Round 2
// 183.996 us; speedup vs baseline: 1.2611x; 1.2611x over previous
//
#include <hip/hip_runtime.h>
#include <hip/hip_bf16.h>
#include <stdint.h>

// ---------------------------------------------------------------------------
// GQA attention block, MI355X/gfx950, bf16 MFMA pipeline.
//   B=8 T=512 C=2048 H=16 KVH=4 D=128
// Round 2: both GEMMs moved to the 8-phase counted-vmcnt 256-class template
// (T1 XCD swizzle + T2 LDS XOR swizzle + T3/T4 phases + T5 setprio).
// ---------------------------------------------------------------------------

typedef __bf16 bf16x8 __attribute__((ext_vector_type(8)));
typedef float  f32x4  __attribute__((ext_vector_type(4)));
typedef float  f4     __attribute__((ext_vector_type(4)));
typedef unsigned short u16x8 __attribute__((ext_vector_type(8)));
typedef unsigned short u16x4 __attribute__((ext_vector_type(4)));
typedef unsigned short us;

template<int V> struct Ic { static constexpr int v = V; };

__device__ __forceinline__ float bf2f(us u) {
  unsigned int x = ((unsigned int)u) << 16;
  return __builtin_bit_cast(float, x);
}
__device__ __forceinline__ us f2bf(float f) {   // round-to-nearest-even
  unsigned int x = __builtin_bit_cast(unsigned int, f);
  unsigned int r = x + 0x7fffu + ((x >> 16) & 1u);
  return (us)(r >> 16);
}

// async global->LDS, 16B per lane; LDS dest must be linear (uniform + lane*16)
__device__ __forceinline__ void gload16(const void* gsrc, void* ldst) {
  auto g = (const __attribute__((address_space(1))) void*)gsrc;
  auto l = (__attribute__((address_space(3))) void*)ldst;
  __builtin_amdgcn_global_load_lds(g, l, 16, 0, 0);
}

#define BAR() __builtin_amdgcn_s_barrier()
#define LGK0() do { asm volatile("s_waitcnt lgkmcnt(0)" ::: "memory"); \
                    __builtin_amdgcn_sched_barrier(0); } while (0)
#define VM0() do { asm volatile("s_waitcnt vmcnt(0)" ::: "memory"); \
                   __builtin_amdgcn_sched_barrier(0); } while (0)

// ---------------------------------------------------------------------------
// small prep kernels
// ---------------------------------------------------------------------------

__global__ void convx_kernel(const float* __restrict__ x, us* __restrict__ xb) {
  size_t idx = (size_t)blockIdx.x * 256 + threadIdx.x;
  const f4* p = (const f4*)(x + idx * 8);
  f4 a = p[0], b = p[1];
  u16x8 o;
#pragma unroll
  for (int e = 0; e < 4; ++e) { o[e] = f2bf(a[e]); o[4 + e] = f2bf(b[e]); }
  *(u16x8*)(xb + idx * 8) = o;
}

// transpose + convert: dst[(rowOff+n)*LD + k] = src[k*N + n], 64x64 LDS tiles
__global__ __launch_bounds__(256) void wtrans_kernel(const float* __restrict__ src,
    us* __restrict__ dst, int N, int rowOff, int LD) {
  __shared__ float lds[64][65];
  const int n0 = blockIdx.x * 64, k0 = blockIdx.y * 64;
  const int c = threadIdx.x & 63, rq = threadIdx.x >> 6;
#pragma unroll
  for (int i = 0; i < 16; ++i) {
    int r = i * 4 + rq;
    lds[r][c] = src[(size_t)(k0 + r) * N + n0 + c];
  }
  __syncthreads();
#pragma unroll
  for (int i = 0; i < 16; ++i) {
    int nr = i * 4 + rq;
    dst[(size_t)(rowOff + n0 + nr) * LD + k0 + c] = f2bf(lds[c][nr]);
  }
}

// RoPE cos/sin tables: [512][64] each, fp32
__global__ void tables_kernel(float* __restrict__ ct, float* __restrict__ st) {
  int idx = blockIdx.x * 256 + threadIdx.x;   // 32768
  int i = idx & 63, t = idx >> 6;
  float inv = exp2f(-(float)i * (13.287712379549449f / 64.0f));
  float ang = (float)t * inv;
  ct[idx] = cosf(ang);
  st[idx] = sinf(ang);
}

// in-place RoPE on Qh [128][512][128] and Kh [32][512][128]; Q scaled
__global__ void rope_kernel(us* __restrict__ Qh, us* __restrict__ Kh,
                            const float* __restrict__ ct, const float* __restrict__ st) {
  int idx = blockIdx.x * 256 + threadIdx.x;   // 1,310,720 exact
  int dq = idx & 15;
  int t = (idx >> 4) & 511;
  int slot = idx >> 13;                       // 0..159
  bool isQ = slot < 128;
  us* rowp = isQ ? (Qh + ((size_t)slot * 512 + t) * 128)
                 : (Kh + ((size_t)(slot - 128) * 512 + t) * 128);
  int d0 = dq * 4;
  u16x4 x1 = *(const u16x4*)(rowp + d0);
  u16x4 x2 = *(const u16x4*)(rowp + 64 + d0);
  f4 c = *(const f4*)(ct + t * 64 + d0);
  f4 s = *(const f4*)(st + t * 64 + d0);
  float scale = isQ ? 0.08838834764831845f : 1.0f;
  u16x4 o1, o2;
#pragma unroll
  for (int e = 0; e < 4; ++e) {
    float a = bf2f(x1[e]), b = bf2f(x2[e]);
    o1[e] = f2bf((a * c[e] - b * s[e]) * scale);
    o2[e] = f2bf((b * c[e] + a * s[e]) * scale);
  }
  *(u16x4*)(rowp + d0) = o1;
  *(u16x4*)(rowp + 64 + d0) = o2;
}

// V [32][512][128] -> Vt [32][128][512]
__global__ __launch_bounds__(256) void vtrans_kernel(const us* __restrict__ Vh,
                                                     us* __restrict__ Vt) {
  __shared__ us lds[64][66];
  const int bid = blockIdx.x;          // 512
  const int bhk = bid >> 4;
  const int rem = bid & 15;
  const int tt = rem >> 1, dt = rem & 1;
  const us* src = Vh + (size_t)bhk * 512 * 128;
  us* dst = Vt + (size_t)bhk * 128 * 512;
  const int c = threadIdx.x & 63, rq = threadIdx.x >> 6;
#pragma unroll
  for (int i = 0; i < 16; ++i) {
    int r = i * 4 + rq;
    lds[r][c] = src[(size_t)(tt * 64 + r) * 128 + dt * 64 + c];
  }
  __syncthreads();
#pragma unroll
  for (int i = 0; i < 16; ++i) {
    int dr = i * 4 + rq;
    dst[(size_t)(dt * 64 + dr) * 512 + tt * 64 + c] = lds[c][dr];
  }
}

// ---------------------------------------------------------------------------
// 8-phase GEMM core. A [M][K], Bt [N][K] bf16, BK=64, iteration = 2 K-tiles.
// 512 threads = 8 waves (WM x WN). Per wave: MF x NF 16x16 output frags.
// LDS: A[2][BM][64] + B[2][BN][64], XOR-swizzled (kc ^= row&7, 16B chunks).
// Staging: K-tile 2i+1 -> buf1 at phases 1-2 (buf1 dead, vmcnt(0) @ph4);
//          K-tile 2i+2 -> buf0 at phases 5-6 (buf0 dead, vmcnt(0) @ph8).
// ---------------------------------------------------------------------------
template<int BM, int BN, int MF, int NF, int GPT, int WN>
__device__ __forceinline__ void gemm8_core(const us* __restrict__ A,
    const us* __restrict__ Bt, int K, int m0, int n0, us* sm,
    f32x4 (&acc)[MF][NF]) {
  constexpr int MH = MF / 2, NH = NF / 2;
  constexpr int ACH = BM * 8, CH2 = (BM + BN) * 4;
  constexpr int BBASE = 2 * BM * 64;     // elements
  const int tid = threadIdx.x, lane = tid & 63, wid = tid >> 6;
  const int wm = wid / WN, wn = wid % WN;
  const int lr = lane & 15, lq = lane >> 4;
  const int NT2 = K >> 7;                // iterations (2 K-tiles each)

  const f32x4 zz = {0.f, 0.f, 0.f, 0.f};
#pragma unroll
  for (int i = 0; i < MF; ++i)
#pragma unroll
    for (int j = 0; j < NF; ++j) acc[i][j] = zz;

  bf16x8 afr[MH][2], bfr[NH][2];

  auto stage_half = [&](int kt, int hf) {
    const int q = kt & 1;
#pragma unroll
    for (int i = 0; i < GPT; ++i) {
      int c = hf * CH2 + i * 512 + tid;
      bool isA = (c < ACH);
      int cc = isA ? c : c - ACH;
      int row = cc >> 3;
      int kcs = (cc & 7) ^ (row & 7);
      const us* src = (isA ? A + (size_t)(m0 + row) * K
                           : Bt + (size_t)(n0 + row) * K) + (kt << 6) + (kcs << 3);
      us* dst = sm + (isA ? q * BM * 64 + cc * 8 : BBASE + q * BN * 64 + cc * 8);
      gload16(src, dst);
    }
  };
  auto lda = [&](int q, int mq) {
#pragma unroll
    for (int f = 0; f < MH; ++f) {
      int R = wm * (MF * 16) + mq * (MH * 16) + f * 16 + lr;
      int base = (q * BM * 64 + R * 64) * 2;
      int sw = (R & 7) << 4;
#pragma unroll
      for (int ks = 0; ks < 2; ++ks)
        afr[f][ks] = *(const bf16x8*)((const char*)sm + base + ((ks * 64 + lq * 16) ^ sw));
    }
  };
  auto ldb = [&](int q, int nq) {
#pragma unroll
    for (int g = 0; g < NH; ++g) {
      int R = wn * (NF * 16) + nq * (NH * 16) + g * 16 + lr;
      int base = (BBASE + q * BN * 64 + R * 64) * 2;
      int sw = (R & 7) << 4;
#pragma unroll
      for (int ks = 0; ks < 2; ++ks)
        bfr[g][ks] = *(const bf16x8*)((const char*)sm + base + ((ks * 64 + lq * 16) ^ sw));
    }
  };
  auto mmac = [&](auto MQ, auto NQ) {
    constexpr int mq = decltype(MQ)::v, nq = decltype(NQ)::v;
    __builtin_amdgcn_s_setprio(1);
#pragma unroll
    for (int ks = 0; ks < 2; ++ks)
#pragma unroll
      for (int f = 0; f < MH; ++f)
#pragma unroll
        for (int g = 0; g < NH; ++g)
          acc[mq * MH + f][nq * NH + g] = __builtin_amdgcn_mfma_f32_16x16x32_bf16(
              afr[f][ks], bfr[g][ks], acc[mq * MH + f][nq * NH + g], 0, 0, 0);
    __builtin_amdgcn_s_setprio(0);
  };

  // prologue: K-tile 0 -> buf0, drain, barrier
  stage_half(0, 0); stage_half(0, 1);
  VM0(); BAR();

  for (int it = 0; it < NT2; ++it) {
    const int k0 = 2 * it;
    const bool pf = (it + 1 < NT2);
    // ---- phases 1-4: compute K-tile k0 (buf0); stage k0+1 -> buf1 @ 1,2 ----
    lda(0, 0); ldb(0, 0);
    stage_half(k0 + 1, 0);
    BAR(); LGK0(); mmac(Ic<0>{}, Ic<0>{}); BAR();

    ldb(0, 1);
    stage_half(k0 + 1, 1);
    BAR(); LGK0(); mmac(Ic<0>{}, Ic<1>{}); BAR();

    lda(0, 1);
    BAR(); LGK0(); mmac(Ic<1>{}, Ic<1>{}); BAR();

    ldb(0, 0);
    BAR(); LGK0(); mmac(Ic<1>{}, Ic<0>{});
    VM0();        // k0+1 fully in buf1 before any wave crosses
    BAR();
    // ---- phases 5-8: compute K-tile k0+1 (buf1); stage k0+2 -> buf0 @ 5,6 --
    lda(1, 0); ldb(1, 0);
    if (pf) stage_half(k0 + 2, 0);
    BAR(); LGK0(); mmac(Ic<0>{}, Ic<0>{}); BAR();

    ldb(1, 1);
    if (pf) stage_half(k0 + 2, 1);
    BAR(); LGK0(); mmac(Ic<0>{}, Ic<1>{}); BAR();

    lda(1, 1);
    BAR(); LGK0(); mmac(Ic<1>{}, Ic<1>{}); BAR();

    ldb(1, 0);
    BAR(); LGK0(); mmac(Ic<1>{}, Ic<0>{});
    VM0();        // k0+2 fully in buf0 before next iteration reads it
    BAR();
  }
}

// QKV GEMM: xb [4096][2048] @ wcat [3072][2048]^T, 256x256 tiles, scatter
__global__ __launch_bounds__(512, 2) void gemm_qkv8_kernel(const us* __restrict__ xb,
    const us* __restrict__ wcat, us* __restrict__ Qh, us* __restrict__ Kh,
    us* __restrict__ Vh) {
  __shared__ __align__(16) us sm[65536];          // 128 KiB
  const int bid = blockIdx.x;                     // 192 = 8 * 24
  const int swz = (bid & 7) * 24 + (bid >> 3);
  const int m0 = (swz & 15) << 8, n0 = (swz >> 4) << 8;
  f32x4 acc[8][4];
  gemm8_core<256, 256, 8, 4, 4, 4>(xb, wcat, 2048, m0, n0, sm, acc);

  const int tid = threadIdx.x, lane = tid & 63, wid = tid >> 6;
  const int wm = wid >> 2, wn = wid & 3, lr = lane & 15, lq = lane >> 4;
#pragma unroll
  for (int f = 0; f < 8; ++f)
#pragma unroll
    for (int g = 0; g < 4; ++g) {
      int col = n0 + wn * 64 + g * 16 + lr;
#pragma unroll
      for (int r = 0; r < 4; ++r) {
        int row = m0 + wm * 128 + f * 16 + lq * 4 + r;
        int bb = row >> 9, t = row & 511;
        us val = f2bf(acc[f][g][r]);
        if (col < 2048) {
          Qh[((size_t)(bb * 16 + (col >> 7)) * 512 + t) * 128 + (col & 127)] = val;
        } else if (col < 2560) {
          int cc = col - 2048;
          Kh[((size_t)(bb * 4 + (cc >> 7)) * 512 + t) * 128 + (cc & 127)] = val;
        } else {
          int cc = col - 2560;
          Vh[((size_t)(bb * 4 + (cc >> 7)) * 512 + t) * 128 + (cc & 127)] = val;
        }
      }
    }
}

// output GEMM: Oh [4096][2048] @ wot [2048][2048]^T -> fp32 out, 256x128 tiles
__global__ __launch_bounds__(512, 2) void gemm_out8_kernel(const us* __restrict__ Ob,
    const us* __restrict__ wot, float* __restrict__ out) {
  __shared__ __align__(16) us sm[49152];          // 96 KiB
  const int bid = blockIdx.x;                     // 256 = 8 * 32
  const int swz = (bid & 7) * 32 + (bid >> 3);
  const int m0 = (swz & 15) << 8, n0 = (swz >> 4) << 7;
  f32x4 acc[4][4];
  gemm8_core<256, 128, 4, 4, 3, 2>(Ob, wot, 2048, m0, n0, sm, acc);

  const int tid = threadIdx.x, lane = tid & 63, wid = tid >> 6;
  const int wm = wid >> 1, wn = wid & 1, lr = lane & 15, lq = lane >> 4;
#pragma unroll
  for (int f = 0; f < 4; ++f)
#pragma unroll
    for (int g = 0; g < 4; ++g) {
      int col = n0 + wn * 64 + g * 16 + lr;
#pragma unroll
      for (int r = 0; r < 4; ++r) {
        int row = m0 + wm * 64 + f * 16 + lq * 4 + r;
        out[(size_t)row * 2048 + col] = acc[f][g][r];
      }
    }
}

// ---------------------------------------------------------------------------
// flash attention (unchanged from round 1): grid (8 qblocks, 128 bh)
// ---------------------------------------------------------------------------
__global__ __launch_bounds__(256) void attn_kernel(const us* __restrict__ Qh,
    const us* __restrict__ Kh, const us* __restrict__ Vt, us* __restrict__ Oh) {
  __shared__ __align__(16) us Ktile[64 * 128];
  __shared__ __align__(16) us Vtile[128 * 64];
  __shared__ __align__(16) us Plds[4 * 16 * 72];
  const int tid = threadIdx.x, lane = tid & 63, w = tid >> 6;
  const int lr = lane & 15, lq = lane >> 4;
  const int qb = blockIdx.x, bh = blockIdx.y;
  const int b = bh >> 4, h = bh & 15, kvh = h >> 2;
  const us* Kbh = Kh + (size_t)(b * 4 + kvh) * 512 * 128;
  const us* Vbh = Vt + (size_t)(b * 4 + kvh) * 128 * 512;

  const us* Qrow = Qh + ((size_t)bh * 512 + qb * 64 + w * 16 + lr) * 128;
  bf16x8 qf[4];
#pragma unroll
  for (int ks = 0; ks < 4; ++ks) qf[ks] = *(const bf16x8*)(Qrow + ks * 32 + (lq << 3));

  const f32x4 zz = {0.f, 0.f, 0.f, 0.f};
  f32x4 o[8];
#pragma unroll
  for (int i = 0; i < 8; ++i) o[i] = zz;
  float m[4], ll[4];
#pragma unroll
  for (int r = 0; r < 4; ++r) { m[r] = -1e30f; ll[r] = 0.f; }
  us* Pw = Plds + w * 16 * 72;

  for (int j = 0; j <= qb; ++j) {
    __syncthreads();
#pragma unroll
    for (int it = 0; it < 4; ++it) {
      int c = it * 256 + tid;
      int row = c >> 4, kc = c & 15;
      gload16(Kbh + (size_t)(j * 64 + row) * 128 + ((kc ^ (row & 7)) << 3),
              Ktile + (c << 3));
    }
#pragma unroll
    for (int it = 0; it < 4; ++it) {
      int c = it * 256 + tid;
      int row = c >> 3, tc = c & 7;
      gload16(Vbh + (size_t)row * 512 + j * 64 + ((tc ^ (row & 7)) << 3),
              Vtile + (c << 3));
    }
    __syncthreads();

    f32x4 s[4];
#pragma unroll
    for (int nb = 0; nb < 4; ++nb) s[nb] = zz;
#pragma unroll
    for (int ks = 0; ks < 4; ++ks) {
#pragma unroll
      for (int nb = 0; nb < 4; ++nb) {
        int row = nb * 16 + lr;
        bf16x8 kf = *(const bf16x8*)(Ktile + (row << 7) + (((ks * 4 + lq) ^ (row & 7)) << 3));
        s[nb] = __builtin_amdgcn_mfma_f32_16x16x32_bf16(qf[ks], kf, s[nb], 0, 0, 0);
      }
    }
    if (j == qb) {
#pragma unroll
      for (int nb = 0; nb < 4; ++nb)
#pragma unroll
        for (int r = 0; r < 4; ++r)
          if (nb * 16 + lr > w * 16 + lq * 4 + r) s[nb][r] = -1e30f;
    }

    float tm[4], alpha[4], rs[4];
#pragma unroll
    for (int r = 0; r < 4; ++r)
      tm[r] = fmaxf(fmaxf(s[0][r], s[1][r]), fmaxf(s[2][r], s[3][r]));
#pragma unroll
    for (int off = 1; off < 16; off <<= 1)
#pragma unroll
      for (int r = 0; r < 4; ++r)
        tm[r] = fmaxf(tm[r], __shfl_xor(tm[r], off, 64));
#pragma unroll
    for (int r = 0; r < 4; ++r) {
      float mn = fmaxf(m[r], tm[r]);
      alpha[r] = __expf(m[r] - mn);
      m[r] = mn;
    }
#pragma unroll
    for (int nb = 0; nb < 4; ++nb)
#pragma unroll
      for (int r = 0; r < 4; ++r)
        s[nb][r] = __expf(s[nb][r] - m[r]);
#pragma unroll
    for (int r = 0; r < 4; ++r)
      rs[r] = s[0][r] + s[1][r] + s[2][r] + s[3][r];
#pragma unroll
    for (int off = 1; off < 16; off <<= 1)
#pragma unroll
      for (int r = 0; r < 4; ++r)
        rs[r] += __shfl_xor(rs[r], off, 64);
#pragma unroll
    for (int r = 0; r < 4; ++r) ll[r] = ll[r] * alpha[r] + rs[r];
#pragma unroll
    for (int i = 0; i < 8; ++i)
#pragma unroll
      for (int r = 0; r < 4; ++r) o[i][r] *= alpha[r];

#pragma unroll
    for (int nb = 0; nb < 4; ++nb)
#pragma unroll
      for (int r = 0; r < 4; ++r)
        Pw[(lq * 4 + r) * 72 + nb * 16 + lr] = f2bf(s[nb][r]);

#pragma unroll
    for (int ks2 = 0; ks2 < 2; ++ks2) {
      bf16x8 pf = *(const bf16x8*)(Pw + lr * 72 + ks2 * 32 + (lq << 3));
#pragma unroll
      for (int nd = 0; nd < 8; ++nd) {
        int d = nd * 16 + lr;
        bf16x8 vf = *(const bf16x8*)(Vtile + (d << 6) + (((ks2 * 4 + lq) ^ (d & 7)) << 3));
        o[nd] = __builtin_amdgcn_mfma_f32_16x16x32_bf16(pf, vf, o[nd], 0, 0, 0);
      }
    }
  }

  float inv[4];
#pragma unroll
  for (int r = 0; r < 4; ++r) inv[r] = 1.0f / ll[r];
  const int rowb = b * 512 + qb * 64 + w * 16 + lq * 4;
  const int colb = h * 128 + lr;
#pragma unroll
  for (int nd = 0; nd < 8; ++nd)
#pragma unroll
    for (int r = 0; r < 4; ++r)
      Oh[(size_t)(rowb + r) * 2048 + colb + nd * 16] = f2bf(o[nd][r] * inv[r]);
}

// ---------------------------------------------------------------------------
extern "C" void kernel_launch(void* const* d_in, const int* in_sizes, int n_in,
                              void* d_out, int out_size, void* d_ws, size_t ws_size,
                              hipStream_t stream) {
  const float* x  = (const float*)d_in[0];
  const float* wq = (const float*)d_in[1];
  const float* wk = (const float*)d_in[2];
  const float* wv = (const float*)d_in[3];
  const float* wo = (const float*)d_in[4];
  float* out = (float*)d_out;
  char* ws = (char*)d_ws;

  us*    xb   = (us*)(ws);                    // [4096][2048] bf16      16 MB
  us*    wcat = (us*)(ws + 16777216);         // [3072][2048] bf16      12 MB
  us*    wot  = (us*)(ws + 29360128);         // [2048][2048] bf16       8 MB
  us*    Qh   = (us*)(ws + 37748736);         // [128][512][128] bf16   16 MB
  us*    Kh   = (us*)(ws + 54525952);         // [32][512][128] bf16     4 MB
  us*    Vh   = (us*)(ws + 58720256);         // [32][512][128] bf16     4 MB
  us*    Vt   = (us*)(ws + 62914560);         // [32][128][512] bf16     4 MB
  us*    Oh   = (us*)(ws + 67108864);         // [4096][2048] bf16      16 MB
  float* ct   = (float*)(ws + 83886080);      // [512][64] fp32
  float* st   = (float*)(ws + 84017152);      // [512][64] fp32

  convx_kernel<<<4096, 256, 0, stream>>>(x, xb);
  wtrans_kernel<<<dim3(32, 32), 256, 0, stream>>>(wq, wcat, 2048, 0, 2048);
  wtrans_kernel<<<dim3(8, 32), 256, 0, stream>>>(wk, wcat, 512, 2048, 2048);
  wtrans_kernel<<<dim3(8, 32), 256, 0, stream>>>(wv, wcat, 512, 2560, 2048);
  wtrans_kernel<<<dim3(32, 32), 256, 0, stream>>>(wo, wot, 2048, 0, 2048);
  tables_kernel<<<128, 256, 0, stream>>>(ct, st);

  gemm_qkv8_kernel<<<192, 512, 0, stream>>>(xb, wcat, Qh, Kh, Vh);
  rope_kernel<<<5120, 256, 0, stream>>>(Qh, Kh, ct, st);
  vtrans_kernel<<<512, 256, 0, stream>>>(Vh, Vt);
  attn_kernel<<<dim3(8, 128), 256, 0, stream>>>(Qh, Kh, Vt, Oh);
  gemm_out8_kernel<<<256, 512, 0, stream>>>(Oh, wot, out);
}

// Round 3
// 174.993 us; speedup vs baseline: 1.3260x; 1.0514x over previous
//
#include <hip/hip_runtime.h>
#include <hip/hip_bf16.h>
#include <stdint.h>

// ---------------------------------------------------------------------------
// GQA attention block, MI355X/gfx950, bf16 MFMA pipeline.
//   B=8 T=512 C=2048 H=16 KVH=4 D=128
// Round 3: counted-vmcnt 8-phase GEMM (true T4). Half-tiles are defined as
// the union over waves of their quadrant rows, so consumption is strictly
// phase-ordered and the waits never drain to 0 in the main loop.
// ---------------------------------------------------------------------------

typedef __bf16 bf16x8 __attribute__((ext_vector_type(8)));
typedef float  f32x4  __attribute__((ext_vector_type(4)));
typedef float  f4     __attribute__((ext_vector_type(4)));
typedef unsigned short u16x8 __attribute__((ext_vector_type(8)));
typedef unsigned short u16x4 __attribute__((ext_vector_type(4)));
typedef unsigned short us;

template<int V> struct Ic { static constexpr int v = V; };

__device__ __forceinline__ float bf2f(us u) {
  unsigned int x = ((unsigned int)u) << 16;
  return __builtin_bit_cast(float, x);
}
__device__ __forceinline__ us f2bf(float f) {   // round-to-nearest-even
  unsigned int x = __builtin_bit_cast(unsigned int, f);
  unsigned int r = x + 0x7fffu + ((x >> 16) & 1u);
  return (us)(r >> 16);
}

// async global->LDS, 16B per lane; LDS dest must be linear (uniform + lane*16)
__device__ __forceinline__ void gload16(const void* gsrc, void* ldst) {
  auto g = (const __attribute__((address_space(1))) void*)gsrc;
  auto l = (__attribute__((address_space(3))) void*)ldst;
  __builtin_amdgcn_global_load_lds(g, l, 16, 0, 0);
}

#define BAR() __builtin_amdgcn_s_barrier()
#define LGK0() do { asm volatile("s_waitcnt lgkmcnt(0)" ::: "memory"); \
                    __builtin_amdgcn_sched_barrier(0); } while (0)

template<int N> __device__ __forceinline__ void VMW() {
  if constexpr (N == 0)      asm volatile("s_waitcnt vmcnt(0)" ::: "memory");
  else if constexpr (N == 2) asm volatile("s_waitcnt vmcnt(2)" ::: "memory");
  else if constexpr (N == 3) asm volatile("s_waitcnt vmcnt(3)" ::: "memory");
  else if constexpr (N == 4) asm volatile("s_waitcnt vmcnt(4)" ::: "memory");
  else static_assert(N == 0 || N == 2 || N == 3 || N == 4, "unsupported vmcnt");
  __builtin_amdgcn_sched_barrier(0);
}

// ---------------------------------------------------------------------------
// small prep kernels
// ---------------------------------------------------------------------------

__global__ void convx_kernel(const float* __restrict__ x, us* __restrict__ xb) {
  size_t idx = (size_t)blockIdx.x * 256 + threadIdx.x;
  const f4* p = (const f4*)(x + idx * 8);
  f4 a = p[0], b = p[1];
  u16x8 o;
#pragma unroll
  for (int e = 0; e < 4; ++e) { o[e] = f2bf(a[e]); o[4 + e] = f2bf(b[e]); }
  *(u16x8*)(xb + idx * 8) = o;
}

// fused transpose+convert of wq,wk,wv,wo. grid (80,32).
//   bx <32: wq -> wcat rows 0..2047 ; 32..39: wk -> +2048 ; 40..47: wv -> +2560
//   bx>=48: wo -> wot
__global__ __launch_bounds__(256) void wtrans_all_kernel(
    const float* __restrict__ wq, const float* __restrict__ wk,
    const float* __restrict__ wv, const float* __restrict__ wo,
    us* __restrict__ wcat, us* __restrict__ wot) {
  __shared__ float lds[64][65];
  int bx = blockIdx.x;
  const float* src; us* dst; int N, rowOff, nb;
  if (bx < 32)      { src = wq; dst = wcat; N = 2048; rowOff = 0;    nb = bx; }
  else if (bx < 40) { src = wk; dst = wcat; N = 512;  rowOff = 2048; nb = bx - 32; }
  else if (bx < 48) { src = wv; dst = wcat; N = 512;  rowOff = 2560; nb = bx - 40; }
  else              { src = wo; dst = wot;  N = 2048; rowOff = 0;    nb = bx - 48; }
  const int n0 = nb * 64, k0 = blockIdx.y * 64;
  const int c = threadIdx.x & 63, rq = threadIdx.x >> 6;
#pragma unroll
  for (int i = 0; i < 16; ++i) {
    int r = i * 4 + rq;
    lds[r][c] = src[(size_t)(k0 + r) * N + n0 + c];
  }
  __syncthreads();
#pragma unroll
  for (int i = 0; i < 16; ++i) {
    int nr = i * 4 + rq;
    dst[(size_t)(rowOff + n0 + nr) * 2048 + k0 + c] = f2bf(lds[c][nr]);
  }
}

// RoPE cos/sin tables: [512][64] each, fp32
__global__ void tables_kernel(float* __restrict__ ct, float* __restrict__ st) {
  int idx = blockIdx.x * 256 + threadIdx.x;   // 32768
  int i = idx & 63, t = idx >> 6;
  float inv = exp2f(-(float)i * (13.287712379549449f / 64.0f));
  float ang = (float)t * inv;
  ct[idx] = cosf(ang);
  st[idx] = sinf(ang);
}

// in-place RoPE on Qh [128][512][128] and Kh [32][512][128]; Q scaled
__global__ void rope_kernel(us* __restrict__ Qh, us* __restrict__ Kh,
                            const float* __restrict__ ct, const float* __restrict__ st) {
  int idx = blockIdx.x * 256 + threadIdx.x;   // 1,310,720 exact
  int dq = idx & 15;
  int t = (idx >> 4) & 511;
  int slot = idx >> 13;                       // 0..159
  bool isQ = slot < 128;
  us* rowp = isQ ? (Qh + ((size_t)slot * 512 + t) * 128)
                 : (Kh + ((size_t)(slot - 128) * 512 + t) * 128);
  int d0 = dq * 4;
  u16x4 x1 = *(const u16x4*)(rowp + d0);
  u16x4 x2 = *(const u16x4*)(rowp + 64 + d0);
  f4 c = *(const f4*)(ct + t * 64 + d0);
  f4 s = *(const f4*)(st + t * 64 + d0);
  float scale = isQ ? 0.08838834764831845f : 1.0f;
  u16x4 o1, o2;
#pragma unroll
  for (int e = 0; e < 4; ++e) {
    float a = bf2f(x1[e]), b = bf2f(x2[e]);
    o1[e] = f2bf((a * c[e] - b * s[e]) * scale);
    o2[e] = f2bf((b * c[e] + a * s[e]) * scale);
  }
  *(u16x4*)(rowp + d0) = o1;
  *(u16x4*)(rowp + 64 + d0) = o2;
}

// V [32][512][128] -> Vt [32][128][512]
__global__ __launch_bounds__(256) void vtrans_kernel(const us* __restrict__ Vh,
                                                     us* __restrict__ Vt) {
  __shared__ us lds[64][66];
  const int bid = blockIdx.x;          // 512
  const int bhk = bid >> 4;
  const int rem = bid & 15;
  const int tt = rem >> 1, dt = rem & 1;
  const us* src = Vh + (size_t)bhk * 512 * 128;
  us* dst = Vt + (size_t)bhk * 128 * 512;
  const int c = threadIdx.x & 63, rq = threadIdx.x >> 6;
#pragma unroll
  for (int i = 0; i < 16; ++i) {
    int r = i * 4 + rq;
    lds[r][c] = src[(size_t)(tt * 64 + r) * 128 + dt * 64 + c];
  }
  __syncthreads();
#pragma unroll
  for (int i = 0; i < 16; ++i) {
    int dr = i * 4 + rq;
    dst[(size_t)(dt * 64 + dr) * 512 + tt * 64 + c] = lds[c][dr];
  }
}

// ---------------------------------------------------------------------------
// 8-phase counted-vmcnt GEMM core. A [M][K], Bt [N][K] bf16, BK=64.
// 512 threads = 8 waves (WM x WN). Wave output = (BM/WM) x (BN/WN).
// LDS halves: A-half h = union over waves of quadrant-mq=h rows;
//             B-half h = union over waves of quadrant-nq=h rows.
// Consumption: ph1 {Ah0,Bh0}, ph2 {Bh1}, ph3 {Ah1}, ph4 {}.
// Staging (tile kt+1 during kt): ph1 Ah0, ph2 Bh0, ph3 Bh1, ph4 Ah1.
// Steady-state waits (before end-of-phase barrier):
//   end-ph1 vmcnt(2*AL), end-ph2 vmcnt(AL+BL), end-ph4 vmcnt(AL+BL).
// ---------------------------------------------------------------------------
template<int BM, int BN, int WM, int WN>
__device__ __forceinline__ void gemm8_core(const us* __restrict__ A,
    const us* __restrict__ Bt, const int K, const int m0, const int n0,
    us* sm, f32x4 (&acc)[BM / (16 * WM)][BN / (16 * WN)]) {
  constexpr int MF = BM / (16 * WM), NF = BN / (16 * WN);
  constexpr int MH = MF / 2, NH = NF / 2;
  constexpr int QM = MH * 16, QN = NH * 16;     // per-wave quarter rows
  constexpr int AHALF = (BM / 2) * 64, ABUF = BM * 64, ALDS = 2 * ABUF;
  constexpr int BHALF = (BN / 2) * 64, BBUF = BN * 64;
  constexpr int AL = BM / 128, BL = BN / 128;   // gloads/thread per half
  const int tid = threadIdx.x, lane = tid & 63, wid = tid >> 6;
  const int wm = wid / WN, wn = wid % WN;
  const int lr = lane & 15, lq = lane >> 4;

  const f32x4 zz = {0.f, 0.f, 0.f, 0.f};
#pragma unroll
  for (int i = 0; i < MF; ++i)
#pragma unroll
    for (int j = 0; j < NF; ++j) acc[i][j] = zz;

  bf16x8 afr[MH][2], bfr[NH][2];

  auto stageA = [&](int kt, int qd, int h) {
#pragma unroll
    for (int i = 0; i < AL; ++i) {
      int c = i * 512 + tid;
      int lrow = c >> 3;
      int grow = (lrow / QM) * (2 * QM) + h * QM + (lrow % QM);
      int kcs = (c & 7) ^ (lrow & 7);
      gload16(A + (size_t)(m0 + grow) * K + (kt << 6) + (kcs << 3),
              sm + qd * ABUF + h * AHALF + c * 8);
    }
  };
  auto stageB = [&](int kt, int qd, int h) {
#pragma unroll
    for (int i = 0; i < BL; ++i) {
      int c = i * 512 + tid;
      int lrow = c >> 3;
      int grow = (lrow / QN) * (2 * QN) + h * QN + (lrow % QN);
      int kcs = (c & 7) ^ (lrow & 7);
      gload16(Bt + (size_t)(n0 + grow) * K + (kt << 6) + (kcs << 3),
              sm + ALDS + qd * BBUF + h * BHALF + c * 8);
    }
  };
  auto lda = [&](int q, int h) {
#pragma unroll
    for (int f = 0; f < MH; ++f) {
      int R = wm * QM + f * 16 + lr;
      const char* base = (const char*)(sm + q * ABUF + h * AHALF + R * 64);
      int sw = (R & 7) << 4;
#pragma unroll
      for (int ks = 0; ks < 2; ++ks)
        afr[f][ks] = *(const bf16x8*)(base + ((ks * 64 + lq * 16) ^ sw));
    }
  };
  auto ldb = [&](int q, int h) {
#pragma unroll
    for (int g = 0; g < NH; ++g) {
      int R = wn * QN + g * 16 + lr;
      const char* base = (const char*)(sm + ALDS + q * BBUF + h * BHALF + R * 64);
      int sw = (R & 7) << 4;
#pragma unroll
      for (int ks = 0; ks < 2; ++ks)
        bfr[g][ks] = *(const bf16x8*)(base + ((ks * 64 + lq * 16) ^ sw));
    }
  };
  auto mmac = [&](auto MQ, auto NQ) {
    constexpr int mq = decltype(MQ)::v, nq = decltype(NQ)::v;
    __builtin_amdgcn_s_setprio(1);
#pragma unroll
    for (int ks = 0; ks < 2; ++ks)
#pragma unroll
      for (int f = 0; f < MH; ++f)
#pragma unroll
        for (int g = 0; g < NH; ++g)
          acc[mq * MH + f][nq * NH + g] = __builtin_amdgcn_mfma_f32_16x16x32_bf16(
              afr[f][ks], bfr[g][ks], acc[mq * MH + f][nq * NH + g], 0, 0, 0);
    __builtin_amdgcn_s_setprio(0);
  };

  // prologue: tile 0 -> buf 0, issue order = consumption order
  stageA(0, 0, 0); stageB(0, 0, 0); stageB(0, 0, 1); stageA(0, 0, 1);
  VMW<AL + BL>(); BAR();

  const int NT = K >> 6;
  for (int kt = 0; kt < NT; ++kt) {
    const int q = kt & 1, qn = q ^ 1;
    const bool pf = (kt + 1 < NT);
    // ---- ph1: quadrant (0,0); reads Ah0,Bh0 ----
    lda(q, 0); ldb(q, 0);
    if (pf) stageA(kt + 1, qn, 0);
    BAR(); LGK0(); mmac(Ic<0>{}, Ic<0>{});
    if (pf) VMW<2 * AL>(); else VMW<AL>();       // next: Bh1(kt)
    BAR();
    // ---- ph2: quadrant (0,1); reads Bh1 ----
    ldb(q, 1);
    if (pf) stageB(kt + 1, qn, 0);
    BAR(); LGK0(); mmac(Ic<0>{}, Ic<1>{});
    if (pf) VMW<AL + BL>(); else VMW<0>();       // next: Ah1(kt)
    BAR();
    // ---- ph3: quadrant (1,1); reads Ah1 ----
    lda(q, 1);
    if (pf) stageB(kt + 1, qn, 1);
    BAR(); LGK0(); mmac(Ic<1>{}, Ic<1>{});
    BAR();                                        // ph4 needs nothing new
    // ---- ph4: quadrant (1,0); re-reads Bh0 ----
    ldb(q, 0);
    if (pf) stageA(kt + 1, qn, 1);
    BAR(); LGK0(); mmac(Ic<1>{}, Ic<0>{});
    if (pf) VMW<AL + BL>();                      // next tile: Ah0,Bh0(kt+1)
    BAR();
  }
}

// QKV GEMM: xb [4096][2048] @ wcat [3072][2048]^T, 256x256 tiles, scatter
__global__ __launch_bounds__(512, 2) void gemm_qkv8_kernel(const us* __restrict__ xb,
    const us* __restrict__ wcat, us* __restrict__ Qh, us* __restrict__ Kh,
    us* __restrict__ Vh) {
  __shared__ __align__(16) us sm[65536];          // 128 KiB
  const int bid = blockIdx.x;                     // 192 = 8 * 24
  const int swz = (bid & 7) * 24 + (bid >> 3);
  const int m0 = (swz & 15) << 8, n0 = (swz >> 4) << 8;
  f32x4 acc[8][4];
  gemm8_core<256, 256, 2, 4>(xb, wcat, 2048, m0, n0, sm, acc);

  const int tid = threadIdx.x, lane = tid & 63, wid = tid >> 6;
  const int wm = wid >> 2, wn = wid & 3, lr = lane & 15, lq = lane >> 4;
#pragma unroll
  for (int f = 0; f < 8; ++f)
#pragma unroll
    for (int g = 0; g < 4; ++g) {
      int col = n0 + wn * 64 + g * 16 + lr;
#pragma unroll
      for (int r = 0; r < 4; ++r) {
        int row = m0 + wm * 128 + f * 16 + lq * 4 + r;
        int bb = row >> 9, t = row & 511;
        us val = f2bf(acc[f][g][r]);
        if (col < 2048) {
          Qh[((size_t)(bb * 16 + (col >> 7)) * 512 + t) * 128 + (col & 127)] = val;
        } else if (col < 2560) {
          int cc = col - 2048;
          Kh[((size_t)(bb * 4 + (cc >> 7)) * 512 + t) * 128 + (cc & 127)] = val;
        } else {
          int cc = col - 2560;
          Vh[((size_t)(bb * 4 + (cc >> 7)) * 512 + t) * 128 + (cc & 127)] = val;
        }
      }
    }
}

// output GEMM: Oh [4096][2048] @ wot [2048][2048]^T -> fp32 out, 256x128 tiles
__global__ __launch_bounds__(512, 2) void gemm_out8_kernel(const us* __restrict__ Ob,
    const us* __restrict__ wot, float* __restrict__ out) {
  __shared__ __align__(16) us sm[49152];          // 96 KiB
  const int bid = blockIdx.x;                     // 256 = 8 * 32
  const int swz = (bid & 7) * 32 + (bid >> 3);
  const int m0 = (swz & 15) << 8, n0 = (swz >> 4) << 7;
  f32x4 acc[8][2];
  gemm8_core<256, 128, 2, 4>(Ob, wot, 2048, m0, n0, sm, acc);

  const int tid = threadIdx.x, lane = tid & 63, wid = tid >> 6;
  const int wm = wid >> 2, wn = wid & 3, lr = lane & 15, lq = lane >> 4;
#pragma unroll
  for (int f = 0; f < 8; ++f)
#pragma unroll
    for (int g = 0; g < 2; ++g) {
      int col = n0 + wn * 32 + g * 16 + lr;
#pragma unroll
      for (int r = 0; r < 4; ++r) {
        int row = m0 + wm * 128 + f * 16 + lq * 4 + r;
        out[(size_t)row * 2048 + col] = acc[f][g][r];
      }
    }
}

// ---------------------------------------------------------------------------
// flash attention (unchanged): grid (8 qblocks, 128 bh)
// ---------------------------------------------------------------------------
__global__ __launch_bounds__(256) void attn_kernel(const us* __restrict__ Qh,
    const us* __restrict__ Kh, const us* __restrict__ Vt, us* __restrict__ Oh) {
  __shared__ __align__(16) us Ktile[64 * 128];
  __shared__ __align__(16) us Vtile[128 * 64];
  __shared__ __align__(16) us Plds[4 * 16 * 72];
  const int tid = threadIdx.x, lane = tid & 63, w = tid >> 6;
  const int lr = lane & 15, lq = lane >> 4;
  const int qb = blockIdx.x, bh = blockIdx.y;
  const int b = bh >> 4, h = bh & 15, kvh = h >> 2;
  const us* Kbh = Kh + (size_t)(b * 4 + kvh) * 512 * 128;
  const us* Vbh = Vt + (size_t)(b * 4 + kvh) * 128 * 512;

  const us* Qrow = Qh + ((size_t)bh * 512 + qb * 64 + w * 16 + lr) * 128;
  bf16x8 qf[4];
#pragma unroll
  for (int ks = 0; ks < 4; ++ks) qf[ks] = *(const bf16x8*)(Qrow + ks * 32 + (lq << 3));

  const f32x4 zz = {0.f, 0.f, 0.f, 0.f};
  f32x4 o[8];
#pragma unroll
  for (int i = 0; i < 8; ++i) o[i] = zz;
  float m[4], ll[4];
#pragma unroll
  for (int r = 0; r < 4; ++r) { m[r] = -1e30f; ll[r] = 0.f; }
  us* Pw = Plds + w * 16 * 72;

  for (int j = 0; j <= qb; ++j) {
    __syncthreads();
#pragma unroll
    for (int it = 0; it < 4; ++it) {
      int c = it * 256 + tid;
      int row = c >> 4, kc = c & 15;
      gload16(Kbh + (size_t)(j * 64 + row) * 128 + ((kc ^ (row & 7)) << 3),
              Ktile + (c << 3));
    }
#pragma unroll
    for (int it = 0; it < 4; ++it) {
      int c = it * 256 + tid;
      int row = c >> 3, tc = c & 7;
      gload16(Vbh + (size_t)row * 512 + j * 64 + ((tc ^ (row & 7)) << 3),
              Vtile + (c << 3));
    }
    __syncthreads();

    f32x4 s[4];
#pragma unroll
    for (int nb = 0; nb < 4; ++nb) s[nb] = zz;
#pragma unroll
    for (int ks = 0; ks < 4; ++ks) {
#pragma unroll
      for (int nb = 0; nb < 4; ++nb) {
        int row = nb * 16 + lr;
        bf16x8 kf = *(const bf16x8*)(Ktile + (row << 7) + (((ks * 4 + lq) ^ (row & 7)) << 3));
        s[nb] = __builtin_amdgcn_mfma_f32_16x16x32_bf16(qf[ks], kf, s[nb], 0, 0, 0);
      }
    }
    if (j == qb) {
#pragma unroll
      for (int nb = 0; nb < 4; ++nb)
#pragma unroll
        for (int r = 0; r < 4; ++r)
          if (nb * 16 + lr > w * 16 + lq * 4 + r) s[nb][r] = -1e30f;
    }

    float tm[4], alpha[4], rs[4];
#pragma unroll
    for (int r = 0; r < 4; ++r)
      tm[r] = fmaxf(fmaxf(s[0][r], s[1][r]), fmaxf(s[2][r], s[3][r]));
#pragma unroll
    for (int off = 1; off < 16; off <<= 1)
#pragma unroll
      for (int r = 0; r < 4; ++r)
        tm[r] = fmaxf(tm[r], __shfl_xor(tm[r], off, 64));
#pragma unroll
    for (int r = 0; r < 4; ++r) {
      float mn = fmaxf(m[r], tm[r]);
      alpha[r] = __expf(m[r] - mn);
      m[r] = mn;
    }
#pragma unroll
    for (int nb = 0; nb < 4; ++nb)
#pragma unroll
      for (int r = 0; r < 4; ++r)
        s[nb][r] = __expf(s[nb][r] - m[r]);
#pragma unroll
    for (int r = 0; r < 4; ++r)
      rs[r] = s[0][r] + s[1][r] + s[2][r] + s[3][r];
#pragma unroll
    for (int off = 1; off < 16; off <<= 1)
#pragma unroll
      for (int r = 0; r < 4; ++r)
        rs[r] += __shfl_xor(rs[r], off, 64);
#pragma unroll
    for (int r = 0; r < 4; ++r) ll[r] = ll[r] * alpha[r] + rs[r];
#pragma unroll
    for (int i = 0; i < 8; ++i)
#pragma unroll
      for (int r = 0; r < 4; ++r) o[i][r] *= alpha[r];

#pragma unroll
    for (int nb = 0; nb < 4; ++nb)
#pragma unroll
      for (int r = 0; r < 4; ++r)
        Pw[(lq * 4 + r) * 72 + nb * 16 + lr] = f2bf(s[nb][r]);

#pragma unroll
    for (int ks2 = 0; ks2 < 2; ++ks2) {
      bf16x8 pf = *(const bf16x8*)(Pw + lr * 72 + ks2 * 32 + (lq << 3));
#pragma unroll
      for (int nd = 0; nd < 8; ++nd) {
        int d = nd * 16 + lr;
        bf16x8 vf = *(const bf16x8*)(Vtile + (d << 6) + (((ks2 * 4 + lq) ^ (d & 7)) << 3));
        o[nd] = __builtin_amdgcn_mfma_f32_16x16x32_bf16(pf, vf, o[nd], 0, 0, 0);
      }
    }
  }

  float inv[4];
#pragma unroll
  for (int r = 0; r < 4; ++r) inv[r] = 1.0f / ll[r];
  const int rowb = b * 512 + qb * 64 + w * 16 + lq * 4;
  const int colb = h * 128 + lr;
#pragma unroll
  for (int nd = 0; nd < 8; ++nd)
#pragma unroll
    for (int r = 0; r < 4; ++r)
      Oh[(size_t)(rowb + r) * 2048 + colb + nd * 16] = f2bf(o[nd][r] * inv[r]);
}

// ---------------------------------------------------------------------------
extern "C" void kernel_launch(void* const* d_in, const int* in_sizes, int n_in,
                              void* d_out, int out_size, void* d_ws, size_t ws_size,
                              hipStream_t stream) {
  const float* x  = (const float*)d_in[0];
  const float* wq = (const float*)d_in[1];
  const float* wk = (const float*)d_in[2];
  const float* wv = (const float*)d_in[3];
  const float* wo = (const float*)d_in[4];
  float* out = (float*)d_out;
  char* ws = (char*)d_ws;

  us*    xb   = (us*)(ws);                    // [4096][2048] bf16      16 MB
  us*    wcat = (us*)(ws + 16777216);         // [3072][2048] bf16      12 MB
  us*    wot  = (us*)(ws + 29360128);         // [2048][2048] bf16       8 MB
  us*    Qh   = (us*)(ws + 37748736);         // [128][512][128] bf16   16 MB
  us*    Kh   = (us*)(ws + 54525952);         // [32][512][128] bf16     4 MB
  us*    Vh   = (us*)(ws + 58720256);         // [32][512][128] bf16     4 MB
  us*    Vt   = (us*)(ws + 62914560);         // [32][128][512] bf16     4 MB
  us*    Oh   = (us*)(ws + 67108864);         // [4096][2048] bf16      16 MB
  float* ct   = (float*)(ws + 83886080);      // [512][64] fp32
  float* st   = (float*)(ws + 84017152);      // [512][64] fp32

  convx_kernel<<<4096, 256, 0, stream>>>(x, xb);
  wtrans_all_kernel<<<dim3(80, 32), 256, 0, stream>>>(wq, wk, wv, wo, wcat, wot);
  tables_kernel<<<128, 256, 0, stream>>>(ct, st);

  gemm_qkv8_kernel<<<192, 512, 0, stream>>>(xb, wcat, Qh, Kh, Vh);
  rope_kernel<<<5120, 256, 0, stream>>>(Qh, Kh, ct, st);
  vtrans_kernel<<<512, 256, 0, stream>>>(Vh, Vt);
  attn_kernel<<<dim3(8, 128), 256, 0, stream>>>(Qh, Kh, Vt, Oh);
  gemm_out8_kernel<<<256, 512, 0, stream>>>(Oh, wot, out);
}